// Round 3
// baseline (314.131 us; speedup 1.0000x reference)
//
#include <hip/hip_runtime.h>
#include <math.h>

// SUFGConv fp32. xc rows [0:2048) are dead; both big einsums stream d_list[:,2048:,:].
// Round-3: barrier-free pipelined passes. Each wave owns a private 4KB LDS quarter
// (stages + reads only its own 32 rows), so __syncthreads is unnecessary; chunk
// residency is enforced with per-wave counted s_waitcnt vmcnt(N) (in-order retire).
// Prefetch depth 2 (double buffer; stage c+2 issued after compute c). B-operand
// (xw/xs) read per-lane from global (L1/L2-resident, 8-way broadcast).

#define DP 2049
#define THRS 0.08628973f   // sqrt(2*ln(2048))/sqrt(2048)

#define XW_OFF 0
#define XS_OFF 131072
#define P1_OFF 524288            // p1: 32 slices * 6144 * 32 = 6291456 floats
#define P2_OFF 6815744           // p2: 64 slices * 2176 * 32 = 4456448 floats

__device__ __forceinline__ void cp4(const float* g, float* l) {
  __builtin_amdgcn_global_load_lds((const __attribute__((address_space(1))) void*)g,
                                   (__attribute__((address_space(3))) void*)l, 4, 0, 0);
}
__device__ __forceinline__ void cp16(const float* g, float* l) {
  __builtin_amdgcn_global_load_lds((const __attribute__((address_space(1))) void*)g,
                                   (__attribute__((address_space(3))) void*)l, 16, 0, 0);
}

__global__ __launch_bounds__(256) void k_pre(const float* __restrict__ x,
                                             const float* __restrict__ wgt,
                                             float* __restrict__ xw) {
  const int gid = blockIdx.x * 256 + threadIdx.x;   // 32768 threads
  const int r = gid >> 3, c0 = (gid & 7) * 4;
  const float* xr = x + (size_t)r * 32;
  float4 acc = {0.f, 0.f, 0.f, 0.f};
#pragma unroll
  for (int f = 0; f < 32; ++f) {
    const float xv = xr[f];
    const float4 wv = *(const float4*)(wgt + f * 32 + c0);
    acc.x = fmaf(xv, wv.x, acc.x); acc.y = fmaf(xv, wv.y, acc.y);
    acc.z = fmaf(xv, wv.z, acc.z); acc.w = fmaf(xv, wv.w, acc.w);
  }
  *(float4*)(xw + (size_t)r * 32 + c0) = acc;
}

__global__ __launch_bounds__(256) void k_pass1(const float* __restrict__ dlist,
                                               const float* __restrict__ xw,
                                               const float* __restrict__ filt,
                                               float* __restrict__ p1) {
  __shared__ float dl[2][4096];                     // 2 x 16KB; wave wv owns [wv*1024..+1023]
  const int tile = blockIdx.x;                      // 0..47  (128 rows)
  const int b    = blockIdx.y;
  const int s    = blockIdx.z;                      // 0..15  (K segment, 128 each)
  const int tid = threadIdx.x, wv = tid >> 6, lane = tid & 63;
  const int r_t = tid >> 3, c_t = tid & 7;
  const int r0 = r_t * 4, c0 = c_t * 4, swzr = r_t & 7;

  const int k_seg = s * 128;
  const float* dbase = dlist + ((size_t)b * 8192 + 2048 + tile * 128) * DP + 1 + k_seg;
  const float* xwb   = xw + ((size_t)b * 2048 + k_seg) * 32;

  const int rhalf = lane >> 5, j = lane & 31, j16 = j >> 2, jrem = j & 3;
  const float* sbase = dbase + (size_t)(wv * 32 + rhalf) * DP + jrem;

  auto stage = [&](int buf, int kc) {               // 16 cp4 per wave
    float* lb = &dl[buf][wv * 1024];
#pragma unroll
    for (int ii = 0; ii < 16; ++ii) {
      const int scol = ((j16 ^ ((ii >> 1) & 7)) << 2);
      cp4(sbase + kc + (size_t)(2 * ii) * DP + scol, lb + ii * 64);
    }
  };

  float4 acc[4];
#pragma unroll
  for (int i = 0; i < 4; ++i) acc[i] = {0.f, 0.f, 0.f, 0.f};

  stage(0, 0);
  stage(1, 32);
#pragma unroll 1
  for (int c = 0; c < 4; ++c) {
    if (c < 3) asm volatile("s_waitcnt vmcnt(16)" ::: "memory");  // chunk c resident, c+1 in flight
    else       asm volatile("s_waitcnt vmcnt(0)"  ::: "memory");
    const float* dbuf = &dl[c & 1][0];
    const float* xwc  = xwb + c * 1024;
#pragma unroll
    for (int k4 = 0; k4 < 8; ++k4) {
      const float4 w0 = *(const float4*)(xwc + (k4 * 4 + 0) * 32 + c0);
      const float4 w1 = *(const float4*)(xwc + (k4 * 4 + 1) * 32 + c0);
      const float4 w2 = *(const float4*)(xwc + (k4 * 4 + 2) * 32 + c0);
      const float4 w3 = *(const float4*)(xwc + (k4 * 4 + 3) * 32 + c0);
      const int colf = ((k4 ^ swzr) << 2);
#pragma unroll
      for (int i = 0; i < 4; ++i) {
        const float4 d = *(const float4*)(dbuf + (r0 + i) * 32 + colf);
        float4& a = acc[i];
        a.x = fmaf(d.x, w0.x, a.x); a.y = fmaf(d.x, w0.y, a.y); a.z = fmaf(d.x, w0.z, a.z); a.w = fmaf(d.x, w0.w, a.w);
        a.x = fmaf(d.y, w1.x, a.x); a.y = fmaf(d.y, w1.y, a.y); a.z = fmaf(d.y, w1.z, a.z); a.w = fmaf(d.y, w1.w, a.w);
        a.x = fmaf(d.z, w2.x, a.x); a.y = fmaf(d.z, w2.y, a.y); a.z = fmaf(d.z, w2.z, a.z); a.w = fmaf(d.z, w2.w, a.w);
        a.x = fmaf(d.w, w3.x, a.x); a.y = fmaf(d.w, w3.y, a.y); a.z = fmaf(d.w, w3.z, a.z); a.w = fmaf(d.w, w3.w, a.w);
      }
    }
    asm volatile("" ::: "memory");                  // order ds_reads before next stage's LDS writes
    if (c + 2 < 4) stage(c & 1, (c + 2) * 32);
  }

  const size_t pbase = ((size_t)(s * 2 + b) * 6144 + tile * 128) * 32;
#pragma unroll
  for (int i = 0; i < 4; ++i) {
    const int m = tile * 128 + r0 + i;
    const float fl = filt[2048 + m];
    float4 v = acc[i];
    v.x *= fl; v.y *= fl; v.z *= fl; v.w *= fl;
    *(float4*)(p1 + pbase + (size_t)(r0 + i) * 32 + c0) = v;
  }
}

__global__ __launch_bounds__(256) void k_shrink(const float* __restrict__ p1,
                                                float* __restrict__ xs) {
  const int f4 = blockIdx.x * 256 + threadIdx.x;    // 384 blocks -> [0, 98304)
  const int row = f4 >> 3;
  const int bb = row / 6144;
  const int m  = row - bb * 6144;
  float4 sum = {0.f, 0.f, 0.f, 0.f};
#pragma unroll
  for (int s = 0; s < 16; ++s) {
    const float4 v = *(const float4*)(p1 + ((size_t)((s * 2 + bb) * 6144 + m) * 8 + (f4 & 7)) * 4);
    sum.x += v.x; sum.y += v.y; sum.z += v.z; sum.w += v.w;
  }
  if (m >= 2048) {
    float t0;
    t0 = fabsf(sum.x) - THRS; sum.x = t0 > 0.f ? copysignf(t0, sum.x) : 0.f;
    t0 = fabsf(sum.y) - THRS; sum.y = t0 > 0.f ? copysignf(t0, sum.y) : 0.f;
    t0 = fabsf(sum.z) - THRS; sum.z = t0 > 0.f ? copysignf(t0, sum.z) : 0.f;
    t0 = fabsf(sum.w) - THRS; sum.w = t0 > 0.f ? copysignf(t0, sum.w) : 0.f;
  }
  *(float4*)(xs + (size_t)f4 * 4) = sum;
}

__global__ __launch_bounds__(256) void k_pass2(const float* __restrict__ dlist,
                                               const float* __restrict__ xs,
                                               float* __restrict__ p2) {
  __shared__ float dl[2][4096];
  const int tile = blockIdx.x;                      // 0..16 (output rows k, 128 each)
  const int b    = blockIdx.y;
  const int s    = blockIdx.z;                      // 0..31 (K segment, 192 each)
  const int tid = threadIdx.x, wv = tid >> 6, lane = tid & 63;
  const int r_t = tid >> 3, c_t = tid & 7;
  const int r0 = r_t * 4, c0 = c_t * 4, swzr = r_t & 7;

  const int m0 = s * 192;
  const float* Abase = dlist + (size_t)b * 8192 * DP + (size_t)2048 * DP + m0;
  const float* xsb   = xs + ((size_t)b * 6144 + m0) * 32;

  const int rloc = lane >> 3, j16 = lane & 7;
  auto stage = [&](int buf, int kc) {               // 4 cp16 per wave
    float* lb = &dl[buf][wv * 1024];
#pragma unroll
    for (int ii = 0; ii < 4; ++ii) {
      const int row_l = wv * 32 + ii * 8 + rloc;
      const int swz = (row_l >> 2) & 7;
      int rowg = tile * 128 + row_l;
      rowg = rowg > 2048 ? 2048 : rowg;             // clamp tail rows (OOB guard)
      cp16(Abase + (size_t)rowg * 6144 + kc + ((j16 ^ swz) << 2), lb + ii * 256);
    }
  };

  float4 acc[4];
#pragma unroll
  for (int i = 0; i < 4; ++i) acc[i] = {0.f, 0.f, 0.f, 0.f};

  stage(0, 0);
  stage(1, 32);
#pragma unroll 1
  for (int c = 0; c < 6; ++c) {
    if (c < 5) asm volatile("s_waitcnt vmcnt(4)" ::: "memory");
    else       asm volatile("s_waitcnt vmcnt(0)" ::: "memory");
    const float* dbuf = &dl[c & 1][0];
    const float* xsc  = xsb + c * 1024;
#pragma unroll
    for (int k4 = 0; k4 < 8; ++k4) {
      const float4 w0 = *(const float4*)(xsc + (k4 * 4 + 0) * 32 + c0);
      const float4 w1 = *(const float4*)(xsc + (k4 * 4 + 1) * 32 + c0);
      const float4 w2 = *(const float4*)(xsc + (k4 * 4 + 2) * 32 + c0);
      const float4 w3 = *(const float4*)(xsc + (k4 * 4 + 3) * 32 + c0);
      const int colf = ((k4 ^ swzr) << 2);
#pragma unroll
      for (int i = 0; i < 4; ++i) {
        const float4 d = *(const float4*)(dbuf + (r0 + i) * 32 + colf);
        float4& a = acc[i];
        a.x = fmaf(d.x, w0.x, a.x); a.y = fmaf(d.x, w0.y, a.y); a.z = fmaf(d.x, w0.z, a.z); a.w = fmaf(d.x, w0.w, a.w);
        a.x = fmaf(d.y, w1.x, a.x); a.y = fmaf(d.y, w1.y, a.y); a.z = fmaf(d.y, w1.z, a.z); a.w = fmaf(d.y, w1.w, a.w);
        a.x = fmaf(d.z, w2.x, a.x); a.y = fmaf(d.z, w2.y, a.y); a.z = fmaf(d.z, w2.z, a.z); a.w = fmaf(d.z, w2.w, a.w);
        a.x = fmaf(d.w, w3.x, a.x); a.y = fmaf(d.w, w3.y, a.y); a.z = fmaf(d.w, w3.z, a.z); a.w = fmaf(d.w, w3.w, a.w);
      }
    }
    asm volatile("" ::: "memory");
    if (c + 2 < 6) stage(c & 1, (c + 2) * 32);
  }

  const size_t pbase = ((size_t)(s * 2 + b) * 2176 + tile * 128) * 32;
#pragma unroll
  for (int i = 0; i < 4; ++i)
    *(float4*)(p2 + pbase + (size_t)(r0 + i) * 32 + c0) = acc[i];
}

__global__ __launch_bounds__(256) void k_reduce(const float* __restrict__ p2,
                                                const float* __restrict__ bias,
                                                float* __restrict__ out) {
  const int idx = blockIdx.x * 256 + threadIdx.x;
  if (idx >= 32784) return;                         // 2*2049*32/4
  const int row = idx >> 3;
  const int bb = row / 2049;
  const int k  = row - bb * 2049;
  const int o4 = idx & 7;
  float4 sum = *(const float4*)(bias + o4 * 4);
#pragma unroll
  for (int s = 0; s < 32; ++s) {
    const float4 v = *(const float4*)(p2 + ((size_t)((s * 2 + bb) * 2176 + k) * 8 + o4) * 4);
    sum.x += v.x; sum.y += v.y; sum.z += v.z; sum.w += v.w;
  }
  *(float4*)(out + (size_t)idx * 4) = sum;
}

extern "C" void kernel_launch(void* const* d_in, const int* in_sizes, int n_in,
                              void* d_out, int out_size, void* d_ws, size_t ws_size,
                              hipStream_t stream) {
  const float* x     = (const float*)d_in[0];
  const float* dlist = (const float*)d_in[1];
  const float* wgt   = (const float*)d_in[2];
  const float* filt  = (const float*)d_in[3];
  const float* bias  = (const float*)d_in[4];
  float* out = (float*)d_out;
  float* ws  = (float*)d_ws;
  float* xw = ws + XW_OFF;
  float* xs = ws + XS_OFF;
  float* p1 = ws + P1_OFF;
  float* p2 = ws + P2_OFF;

  k_pre   <<<dim3(128),        dim3(256), 0, stream>>>(x, wgt, xw);
  k_pass1 <<<dim3(48, 2, 16),  dim3(256), 0, stream>>>(dlist, xw, filt, p1);
  k_shrink<<<dim3(384),        dim3(256), 0, stream>>>(p1, xs);
  k_pass2 <<<dim3(17, 2, 32),  dim3(256), 0, stream>>>(dlist, xs, p2);
  k_reduce<<<dim3(129),        dim3(256), 0, stream>>>(p2, bias, out);
}

// Round 4
// 270.532 us; speedup vs baseline: 1.1612x; 1.1612x over previous
//
#include <hip/hip_runtime.h>
#include <math.h>

// SUFGConv fp32. xc rows [0:2048) are dead; both big einsums stream d_list[:,2048:,:].
// Round-4: back to barrier double-buffer (R2-validated staging + swizzle), with
// register pressure capped via __launch_bounds__(256,4) (VGPR<=128 -> 4 waves/SIMD)
// and rolled stage loops. Latency hiding comes from TLP (3-4 blocks/CU resident),
// not per-wave asm pipelining (R3: VGPR 160 -> 2 waves/SIMD -> 88us. Do not repeat).
//
// LDS: A-tile only, XOR-swizzled at 16B grain on BOTH stage-src and ds_read addr
// (same involution -> conflict-free, validated R2/R3: SQ_LDS_BANK_CONFLICT=0).
// B (xw/xs, 256KB-768KB) read per-lane from global, L1/L2-served 8-way broadcast.

#define DP 2049
#define THRS 0.08628973f   // sqrt(2*ln(2048))/sqrt(2048)

#define XW_OFF 0
#define XS_OFF 131072
#define P1_OFF 524288            // p1: 16 slices * 6144 * 32 = 3145728 floats
#define P2_OFF 3670016           // p2: 64 slices * 2176 * 32 = 4456448 floats

__device__ __forceinline__ void cp4(const float* g, float* l) {
  __builtin_amdgcn_global_load_lds((const __attribute__((address_space(1))) void*)g,
                                   (__attribute__((address_space(3))) void*)l, 4, 0, 0);
}
__device__ __forceinline__ void cp16(const float* g, float* l) {
  __builtin_amdgcn_global_load_lds((const __attribute__((address_space(1))) void*)g,
                                   (__attribute__((address_space(3))) void*)l, 16, 0, 0);
}

__global__ __launch_bounds__(256) void k_pre(const float* __restrict__ x,
                                             const float* __restrict__ wgt,
                                             float* __restrict__ xw) {
  const int gid = blockIdx.x * 256 + threadIdx.x;   // 32768 threads
  const int r = gid >> 3, c0 = (gid & 7) * 4;
  const float* xr = x + (size_t)r * 32;
  float4 acc = {0.f, 0.f, 0.f, 0.f};
#pragma unroll
  for (int f = 0; f < 32; ++f) {
    const float xv = xr[f];
    const float4 wv = *(const float4*)(wgt + f * 32 + c0);
    acc.x = fmaf(xv, wv.x, acc.x); acc.y = fmaf(xv, wv.y, acc.y);
    acc.z = fmaf(xv, wv.z, acc.z); acc.w = fmaf(xv, wv.w, acc.w);
  }
  *(float4*)(xw + (size_t)r * 32 + c0) = acc;
}

__global__ __launch_bounds__(256, 4) void k_pass1(const float* __restrict__ dlist,
                                                  const float* __restrict__ xw,
                                                  const float* __restrict__ filt,
                                                  float* __restrict__ p1) {
  __shared__ float dl[2][4096];                     // 2 x 16KB; wave wv owns [wv*1024..+1023]
  const int tile = blockIdx.x;                      // 0..47  (128 rows)
  const int b    = blockIdx.y;
  const int s    = blockIdx.z;                      // 0..7   (K segment, 256 each)
  const int tid = threadIdx.x, wv = tid >> 6, lane = tid & 63;
  const int r_t = tid >> 3, c_t = tid & 7;
  const int r0 = r_t * 4, c0 = c_t * 4, swzr = r_t & 7;

  const int k_seg = s * 256;
  const float* dbase = dlist + ((size_t)b * 8192 + 2048 + tile * 128) * DP + 1 + k_seg;
  const float* xwb   = xw + ((size_t)b * 2048 + k_seg) * 32;

  const int rhalf = lane >> 5, j = lane & 31, j16 = j >> 2, jrem = j & 3;
  const float* sbase = dbase + (size_t)(wv * 32 + rhalf) * DP + jrem;

  auto stage = [&](int buf, int kc) {               // 16 cp4 per wave, rolled 4x
    float* lb = &dl[buf][wv * 1024];
#pragma unroll 4
    for (int ii = 0; ii < 16; ++ii) {
      const int scol = ((j16 ^ ((ii >> 1) & 7)) << 2);
      cp4(sbase + kc + (size_t)(2 * ii) * DP + scol, lb + ii * 64);
    }
  };

  float4 acc[4];
#pragma unroll
  for (int i = 0; i < 4; ++i) acc[i] = {0.f, 0.f, 0.f, 0.f};

  stage(0, 0);
#pragma unroll 1
  for (int c = 0; c < 8; ++c) {
    __syncthreads();                                // chunk c resident
    if (c < 7) stage((c + 1) & 1, (c + 1) * 32);    // prefetch flies under compute
    const float* dbuf = &dl[c & 1][0];
    const float* xwc  = xwb + c * 1024;
#pragma unroll
    for (int k4 = 0; k4 < 8; ++k4) {
      const float4 w0 = *(const float4*)(xwc + (k4 * 4 + 0) * 32 + c0);
      const float4 w1 = *(const float4*)(xwc + (k4 * 4 + 1) * 32 + c0);
      const float4 w2 = *(const float4*)(xwc + (k4 * 4 + 2) * 32 + c0);
      const float4 w3 = *(const float4*)(xwc + (k4 * 4 + 3) * 32 + c0);
      const int colf = ((k4 ^ swzr) << 2);
#pragma unroll
      for (int i = 0; i < 4; ++i) {
        const float4 d = *(const float4*)(dbuf + (r0 + i) * 32 + colf);
        float4& a = acc[i];
        a.x = fmaf(d.x, w0.x, a.x); a.y = fmaf(d.x, w0.y, a.y); a.z = fmaf(d.x, w0.z, a.z); a.w = fmaf(d.x, w0.w, a.w);
        a.x = fmaf(d.y, w1.x, a.x); a.y = fmaf(d.y, w1.y, a.y); a.z = fmaf(d.y, w1.z, a.z); a.w = fmaf(d.y, w1.w, a.w);
        a.x = fmaf(d.z, w2.x, a.x); a.y = fmaf(d.z, w2.y, a.y); a.z = fmaf(d.z, w2.z, a.z); a.w = fmaf(d.z, w2.w, a.w);
        a.x = fmaf(d.w, w3.x, a.x); a.y = fmaf(d.w, w3.y, a.y); a.z = fmaf(d.w, w3.z, a.z); a.w = fmaf(d.w, w3.w, a.w);
      }
    }
  }

  const size_t pbase = ((size_t)(s * 2 + b) * 6144 + tile * 128) * 32;
#pragma unroll
  for (int i = 0; i < 4; ++i) {
    const int m = tile * 128 + r0 + i;
    const float fl = filt[2048 + m];
    float4 v = acc[i];
    v.x *= fl; v.y *= fl; v.z *= fl; v.w *= fl;
    *(float4*)(p1 + pbase + (size_t)(r0 + i) * 32 + c0) = v;
  }
}

__global__ __launch_bounds__(256) void k_shrink(const float* __restrict__ p1,
                                                float* __restrict__ xs) {
  const int f4 = blockIdx.x * 256 + threadIdx.x;    // 384 blocks -> [0, 98304)
  const int row = f4 >> 3;
  const int bb = row / 6144;
  const int m  = row - bb * 6144;
  float4 sum = {0.f, 0.f, 0.f, 0.f};
#pragma unroll
  for (int s = 0; s < 8; ++s) {
    const float4 v = *(const float4*)(p1 + ((size_t)((s * 2 + bb) * 6144 + m) * 8 + (f4 & 7)) * 4);
    sum.x += v.x; sum.y += v.y; sum.z += v.z; sum.w += v.w;
  }
  if (m >= 2048) {
    float t0;
    t0 = fabsf(sum.x) - THRS; sum.x = t0 > 0.f ? copysignf(t0, sum.x) : 0.f;
    t0 = fabsf(sum.y) - THRS; sum.y = t0 > 0.f ? copysignf(t0, sum.y) : 0.f;
    t0 = fabsf(sum.z) - THRS; sum.z = t0 > 0.f ? copysignf(t0, sum.z) : 0.f;
    t0 = fabsf(sum.w) - THRS; sum.w = t0 > 0.f ? copysignf(t0, sum.w) : 0.f;
  }
  *(float4*)(xs + (size_t)f4 * 4) = sum;
}

__global__ __launch_bounds__(256, 4) void k_pass2(const float* __restrict__ dlist,
                                                  const float* __restrict__ xs,
                                                  float* __restrict__ p2) {
  __shared__ float dl[2][4096];
  const int tile = blockIdx.x;                      // 0..16 (output rows k, 128 each)
  const int b    = blockIdx.y;
  const int s    = blockIdx.z;                      // 0..31 (K segment, 192 each)
  const int tid = threadIdx.x, wv = tid >> 6, lane = tid & 63;
  const int r_t = tid >> 3, c_t = tid & 7;
  const int r0 = r_t * 4, c0 = c_t * 4, swzr = r_t & 7;

  const int m0 = s * 192;
  const float* Abase = dlist + (size_t)b * 8192 * DP + (size_t)2048 * DP + m0;
  const float* xsb   = xs + ((size_t)b * 6144 + m0) * 32;

  const int rloc = lane >> 3, j16 = lane & 7;
  auto stage = [&](int buf, int kc) {               // 4 cp16 per wave
    float* lb = &dl[buf][wv * 1024];
#pragma unroll
    for (int ii = 0; ii < 4; ++ii) {
      const int row_l = wv * 32 + ii * 8 + rloc;
      const int swz = (row_l >> 2) & 7;
      int rowg = tile * 128 + row_l;
      rowg = rowg > 2048 ? 2048 : rowg;             // clamp tail rows (OOB guard)
      cp16(Abase + (size_t)rowg * 6144 + kc + ((j16 ^ swz) << 2), lb + ii * 256);
    }
  };

  float4 acc[4];
#pragma unroll
  for (int i = 0; i < 4; ++i) acc[i] = {0.f, 0.f, 0.f, 0.f};

  stage(0, 0);
#pragma unroll 1
  for (int c = 0; c < 6; ++c) {
    __syncthreads();
    if (c < 5) stage((c + 1) & 1, (c + 1) * 32);
    const float* dbuf = &dl[c & 1][0];
    const float* xsc  = xsb + c * 1024;
#pragma unroll
    for (int k4 = 0; k4 < 8; ++k4) {
      const float4 w0 = *(const float4*)(xsc + (k4 * 4 + 0) * 32 + c0);
      const float4 w1 = *(const float4*)(xsc + (k4 * 4 + 1) * 32 + c0);
      const float4 w2 = *(const float4*)(xsc + (k4 * 4 + 2) * 32 + c0);
      const float4 w3 = *(const float4*)(xsc + (k4 * 4 + 3) * 32 + c0);
      const int colf = ((k4 ^ swzr) << 2);
#pragma unroll
      for (int i = 0; i < 4; ++i) {
        const float4 d = *(const float4*)(dbuf + (r0 + i) * 32 + colf);
        float4& a = acc[i];
        a.x = fmaf(d.x, w0.x, a.x); a.y = fmaf(d.x, w0.y, a.y); a.z = fmaf(d.x, w0.z, a.z); a.w = fmaf(d.x, w0.w, a.w);
        a.x = fmaf(d.y, w1.x, a.x); a.y = fmaf(d.y, w1.y, a.y); a.z = fmaf(d.y, w1.z, a.z); a.w = fmaf(d.y, w1.w, a.w);
        a.x = fmaf(d.z, w2.x, a.x); a.y = fmaf(d.z, w2.y, a.y); a.z = fmaf(d.z, w2.z, a.z); a.w = fmaf(d.z, w2.w, a.w);
        a.x = fmaf(d.w, w3.x, a.x); a.y = fmaf(d.w, w3.y, a.y); a.z = fmaf(d.w, w3.z, a.z); a.w = fmaf(d.w, w3.w, a.w);
      }
    }
  }

  const size_t pbase = ((size_t)(s * 2 + b) * 2176 + tile * 128) * 32;
#pragma unroll
  for (int i = 0; i < 4; ++i)
    *(float4*)(p2 + pbase + (size_t)(r0 + i) * 32 + c0) = acc[i];
}

__global__ __launch_bounds__(256) void k_reduce(const float* __restrict__ p2,
                                                const float* __restrict__ bias,
                                                float* __restrict__ out) {
  const int idx = blockIdx.x * 256 + threadIdx.x;
  if (idx >= 32784) return;                         // 2*2049*32/4
  const int row = idx >> 3;
  const int bb = row / 2049;
  const int k  = row - bb * 2049;
  const int o4 = idx & 7;
  float4 sum = *(const float4*)(bias + o4 * 4);
#pragma unroll
  for (int s = 0; s < 32; ++s) {
    const float4 v = *(const float4*)(p2 + ((size_t)((s * 2 + bb) * 2176 + k) * 8 + o4) * 4);
    sum.x += v.x; sum.y += v.y; sum.z += v.z; sum.w += v.w;
  }
  *(float4*)(out + (size_t)idx * 4) = sum;
}

extern "C" void kernel_launch(void* const* d_in, const int* in_sizes, int n_in,
                              void* d_out, int out_size, void* d_ws, size_t ws_size,
                              hipStream_t stream) {
  const float* x     = (const float*)d_in[0];
  const float* dlist = (const float*)d_in[1];
  const float* wgt   = (const float*)d_in[2];
  const float* filt  = (const float*)d_in[3];
  const float* bias  = (const float*)d_in[4];
  float* out = (float*)d_out;
  float* ws  = (float*)d_ws;
  float* xw = ws + XW_OFF;
  float* xs = ws + XS_OFF;
  float* p1 = ws + P1_OFF;
  float* p2 = ws + P2_OFF;

  k_pre   <<<dim3(128),       dim3(256), 0, stream>>>(x, wgt, xw);
  k_pass1 <<<dim3(48, 2, 8),  dim3(256), 0, stream>>>(dlist, xw, filt, p1);
  k_shrink<<<dim3(384),       dim3(256), 0, stream>>>(p1, xs);
  k_pass2 <<<dim3(17, 2, 32), dim3(256), 0, stream>>>(dlist, xs, p2);
  k_reduce<<<dim3(129),       dim3(256), 0, stream>>>(p2, bias, out);
}

// Round 5
// 269.550 us; speedup vs baseline: 1.1654x; 1.0036x over previous
//
#include <hip/hip_runtime.h>
#include <math.h>

// SUFGConv fp32 via split-bf16 MFMA. xc rows [0:2048) are dead; both big einsums
// stream d_list[:,2048:,:] (100MB each, L3-resident after first touch).
//
// R5 structure: NO LDS, NO barriers. Each wave owns a 32x32 output tile of
// mfma_f32_32x32x16_bf16. A (d_list, fp32) is gathered straight into fragments
// (lane: row=lane&31, k-octet=(lane>>5)*8) and hi/lo-split in registers
// (v_cvt_pk_bf16_f32). B (xw / x_shrink) is precomputed as transposed bf16
// hi/lo arrays [b][col][k] so one B-fragment = one 16B L1-hot load.
// acc += Ah*Bh + Al*Bh + Ah*Bl  (fp32 accumulate; dropped Al*Bl ~2^-18 rel).
//
// R1-R4 lesson: barrier-coupled global_load_lds staging pinned both passes at
// ~65us regardless of LDS traffic/occupancy/vmcnt tuning. Do not reintroduce.

#define DP 2049
#define THRS 0.08628973f   // sqrt(2*ln(2048))/sqrt(2048)

typedef float  f32x4  __attribute__((ext_vector_type(4)));
typedef float  f32x16 __attribute__((ext_vector_type(16)));
typedef short  s16x8  __attribute__((ext_vector_type(8)));
typedef unsigned short u16;

// ws byte offsets
#define XWT_H 0u            // [2][32][2048] u16
#define XWT_L 262144u
#define XST_H 524288u       // [2][32][6144] u16
#define XST_L 1310720u
#define P1_B  2097152u      // [16][32][6144] f32 (slice = s*2+b)
#define P2_B  14680064u     // [48][32][2176] f32

union U8 { unsigned u[4]; s16x8 v; };

__device__ __forceinline__ unsigned cvtpk(float a, float b) {
  unsigned r;
  asm("v_cvt_pk_bf16_f32 %0, %1, %2" : "=v"(r) : "v"(a), "v"(b));
  return r;
}
__device__ __forceinline__ void split2(float a0, float a1, unsigned& h, unsigned& l) {
  h = cvtpk(a0, a1);
  const float f0 = __uint_as_float(h << 16);
  const float f1 = __uint_as_float(h & 0xFFFF0000u);
  l = cvtpk(a0 - f0, a1 - f1);
}
__device__ __forceinline__ f32x4 ld4u(const float* p) {  // 4B-aligned 16B load
  f32x4 r; __builtin_memcpy(&r, p, 16); return r;
}

// xwT = transpose(x @ weight), split to bf16 hi/lo, [b][col][n]
__global__ __launch_bounds__(256) void k_pre(const float* __restrict__ x,
                                             const float* __restrict__ wgt,
                                             u16* __restrict__ xwt_h,
                                             u16* __restrict__ xwt_l) {
  const int idx = blockIdx.x * 256 + threadIdx.x;   // 16384 threads
  const int n0  = (idx & 255) * 8;
  const int col = (idx >> 8) & 31;
  const int b   = idx >> 13;
  const float* xr = x + ((size_t)b * 2048 + n0) * 32;
  float acc[8];
#pragma unroll
  for (int j = 0; j < 8; ++j) acc[j] = 0.f;
#pragma unroll 8
  for (int f = 0; f < 32; ++f) {
    const float wf = wgt[f * 32 + col];
#pragma unroll
    for (int j = 0; j < 8; ++j) acc[j] = fmaf(xr[j * 32 + f], wf, acc[j]);
  }
  U8 H, L;
#pragma unroll
  for (int p = 0; p < 4; ++p) split2(acc[2 * p], acc[2 * p + 1], H.u[p], L.u[p]);
  const size_t o = ((size_t)b * 32 + col) * 2048 + n0;
  *(s16x8*)(xwt_h + o) = H.v;
  *(s16x8*)(xwt_l + o) = L.v;
}

// p1[(s,b)][col][m] = (d1_seg @ xw) * filt   -- 128 rows x 32 cols per block
__global__ __launch_bounds__(256, 4) void k_pass1(const float* __restrict__ dlist,
                                                  const u16* __restrict__ xwt_h,
                                                  const u16* __restrict__ xwt_l,
                                                  const float* __restrict__ filt,
                                                  float* __restrict__ p1) {
  const int mt = blockIdx.x, b = blockIdx.y, s = blockIdx.z;   // 48, 2, 8
  const int tid = threadIdx.x, wv = tid >> 6, lane = tid & 63;
  const int rc = lane & 31, oct = lane >> 5;      // A-row / C-col ; k-octet
  const int m_a = mt * 128 + wv * 32 + rc;
  const int k0 = s * 256;

  const float* A  = dlist + ((size_t)(b * 8192 + 2048 + m_a)) * DP + 1 + k0 + oct * 8;
  const u16*   Bh = xwt_h + ((size_t)b * 32 + rc) * 2048 + k0 + oct * 8;
  const u16*   Bl = xwt_l + ((size_t)b * 32 + rc) * 2048 + k0 + oct * 8;

  f32x16 acc = {0.f,0.f,0.f,0.f,0.f,0.f,0.f,0.f,0.f,0.f,0.f,0.f,0.f,0.f,0.f,0.f};
#pragma unroll 2
  for (int st = 0; st < 16; ++st) {
    const f32x4 a0 = ld4u(A + st * 16);
    const f32x4 a1 = ld4u(A + st * 16 + 4);
    U8 Ah, Al;
    split2(a0.x, a0.y, Ah.u[0], Al.u[0]);
    split2(a0.z, a0.w, Ah.u[1], Al.u[1]);
    split2(a1.x, a1.y, Ah.u[2], Al.u[2]);
    split2(a1.z, a1.w, Ah.u[3], Al.u[3]);
    const s16x8 bh = *(const s16x8*)(Bh + st * 16);
    const s16x8 bl = *(const s16x8*)(Bl + st * 16);
    acc = __builtin_amdgcn_mfma_f32_32x32x16_bf16(Ah.v, bh, acc, 0, 0, 0);
    acc = __builtin_amdgcn_mfma_f32_32x32x16_bf16(Al.v, bh, acc, 0, 0, 0);
    acc = __builtin_amdgcn_mfma_f32_32x32x16_bf16(Ah.v, bl, acc, 0, 0, 0);
  }

  // C layout: col = lane&31, row = (reg&3) + 8*(reg>>2) + 4*oct
  float* pc = p1 + ((size_t)((s * 2 + b) * 32 + rc)) * 6144 + mt * 128 + wv * 32 + 4 * oct;
  const float* fb = filt + 2048 + mt * 128 + wv * 32 + 4 * oct;
#pragma unroll
  for (int g = 0; g < 4; ++g) {
    const f32x4 fv = *(const f32x4*)(fb + 8 * g);
    f32x4 v;
    v.x = acc[4 * g + 0] * fv.x; v.y = acc[4 * g + 1] * fv.y;
    v.z = acc[4 * g + 2] * fv.z; v.w = acc[4 * g + 3] * fv.w;
    *(f32x4*)(pc + 8 * g) = v;
  }
}

// xsT = shrink(sum_s p1), split bf16 hi/lo, [b][col][m]
__global__ __launch_bounds__(256) void k_shrink(const float* __restrict__ p1,
                                                u16* __restrict__ xst_h,
                                                u16* __restrict__ xst_l) {
  const int idx = blockIdx.x * 256 + threadIdx.x;   // 49152 threads
  const int m0  = (idx % 768) * 8;
  const int col = (idx / 768) % 32;
  const int b   = idx / 24576;
  f32x4 s0 = {0.f,0.f,0.f,0.f}, s1 = {0.f,0.f,0.f,0.f};
#pragma unroll
  for (int s = 0; s < 8; ++s) {
    const float* pr = p1 + ((size_t)((s * 2 + b) * 32 + col)) * 6144 + m0;
    const f32x4 v0 = *(const f32x4*)pr;
    const f32x4 v1 = *(const f32x4*)(pr + 4);
    s0 += v0; s1 += v1;
  }
  float a[8] = {s0.x, s0.y, s0.z, s0.w, s1.x, s1.y, s1.z, s1.w};
  if (m0 >= 2048) {
#pragma unroll
    for (int j = 0; j < 8; ++j) {
      const float t = fabsf(a[j]) - THRS;
      a[j] = t > 0.f ? copysignf(t, a[j]) : 0.f;
    }
  }
  U8 H, L;
#pragma unroll
  for (int p = 0; p < 4; ++p) split2(a[2 * p], a[2 * p + 1], H.u[p], L.u[p]);
  const size_t o = ((size_t)b * 32 + col) * 6144 + m0;
  *(s16x8*)(xst_h + o) = H.v;
  *(s16x8*)(xst_l + o) = L.v;
}

// p2[(s,b)][col][k] = y2_seg @ x_shrink
__global__ __launch_bounds__(256, 4) void k_pass2(const float* __restrict__ dlist,
                                                  const u16* __restrict__ xst_h,
                                                  const u16* __restrict__ xst_l,
                                                  float* __restrict__ p2) {
  const int kt = blockIdx.x, b = blockIdx.y, s = blockIdx.z;   // 17, 2, 24
  const int tid = threadIdx.x, wv = tid >> 6, lane = tid & 63;
  const int rc = lane & 31, oct = lane >> 5;
  int krow = kt * 128 + wv * 32 + rc;
  if (krow > 2048) krow = 2048;                    // clamp; padded rows discarded
  const int m0 = s * 256;

  const float* A  = dlist + (size_t)b * 8192 * DP + (size_t)2048 * DP
                  + (size_t)krow * 6144 + m0 + oct * 8;
  const u16*   Bh = xst_h + ((size_t)b * 32 + rc) * 6144 + m0 + oct * 8;
  const u16*   Bl = xst_l + ((size_t)b * 32 + rc) * 6144 + m0 + oct * 8;

  f32x16 acc = {0.f,0.f,0.f,0.f,0.f,0.f,0.f,0.f,0.f,0.f,0.f,0.f,0.f,0.f,0.f,0.f};
#pragma unroll 2
  for (int st = 0; st < 16; ++st) {
    const f32x4 a0 = *(const f32x4*)(A + st * 16);      // 16B-aligned here
    const f32x4 a1 = *(const f32x4*)(A + st * 16 + 4);
    U8 Ah, Al;
    split2(a0.x, a0.y, Ah.u[0], Al.u[0]);
    split2(a0.z, a0.w, Ah.u[1], Al.u[1]);
    split2(a1.x, a1.y, Ah.u[2], Al.u[2]);
    split2(a1.z, a1.w, Ah.u[3], Al.u[3]);
    const s16x8 bh = *(const s16x8*)(Bh + st * 16);
    const s16x8 bl = *(const s16x8*)(Bl + st * 16);
    acc = __builtin_amdgcn_mfma_f32_32x32x16_bf16(Ah.v, bh, acc, 0, 0, 0);
    acc = __builtin_amdgcn_mfma_f32_32x32x16_bf16(Al.v, bh, acc, 0, 0, 0);
    acc = __builtin_amdgcn_mfma_f32_32x32x16_bf16(Ah.v, bl, acc, 0, 0, 0);
  }

  float* pc = p2 + ((size_t)((s * 2 + b) * 32 + rc)) * 2176 + kt * 128 + wv * 32 + 4 * oct;
#pragma unroll
  for (int g = 0; g < 4; ++g) {
    f32x4 v;
    v.x = acc[4 * g + 0]; v.y = acc[4 * g + 1];
    v.z = acc[4 * g + 2]; v.w = acc[4 * g + 3];
    *(f32x4*)(pc + 8 * g) = v;
  }
}

// out[b][k][col] = bias[col] + sum_s p2[(s,b)][col][k]
__global__ __launch_bounds__(256) void k_reduce(const float* __restrict__ p2,
                                                const float* __restrict__ bias,
                                                float* __restrict__ out) {
  const int idx = blockIdx.x * 256 + threadIdx.x;   // 34816 threads
  if (idx >= 34816) return;
  const int k4  = idx % 544;
  const int col = (idx / 544) % 32;
  const int b   = idx / 17408;
  const int k0r = k4 * 4;
  f32x4 sum = {0.f,0.f,0.f,0.f};
#pragma unroll 8
  for (int s = 0; s < 24; ++s)
    sum += *(const f32x4*)(p2 + ((size_t)((s * 2 + b) * 32 + col)) * 2176 + k0r);
  const float bv = bias[col];
#pragma unroll
  for (int j = 0; j < 4; ++j) {
    const int k = k0r + j;
    if (k <= 2048) out[((size_t)b * 2049 + k) * 32 + col] = sum[j] + bv;
  }
}

extern "C" void kernel_launch(void* const* d_in, const int* in_sizes, int n_in,
                              void* d_out, int out_size, void* d_ws, size_t ws_size,
                              hipStream_t stream) {
  const float* x     = (const float*)d_in[0];
  const float* dlist = (const float*)d_in[1];
  const float* wgt   = (const float*)d_in[2];
  const float* filt  = (const float*)d_in[3];
  const float* bias  = (const float*)d_in[4];
  float* out = (float*)d_out;
  char*  ws  = (char*)d_ws;
  u16*   xwt_h = (u16*)(ws + XWT_H);
  u16*   xwt_l = (u16*)(ws + XWT_L);
  u16*   xst_h = (u16*)(ws + XST_H);
  u16*   xst_l = (u16*)(ws + XST_L);
  float* p1    = (float*)(ws + P1_B);
  float* p2    = (float*)(ws + P2_B);

  k_pre   <<<dim3(64),         dim3(256), 0, stream>>>(x, wgt, xwt_h, xwt_l);
  k_pass1 <<<dim3(48, 2, 8),   dim3(256), 0, stream>>>(dlist, xwt_h, xwt_l, filt, p1);
  k_shrink<<<dim3(192),        dim3(256), 0, stream>>>(p1, xst_h, xst_l);
  k_pass2 <<<dim3(17, 2, 24),  dim3(256), 0, stream>>>(dlist, xst_h, xst_l, p2);
  k_reduce<<<dim3(136),        dim3(256), 0, stream>>>(p2, bias, out);
}

// Round 6
// 257.778 us; speedup vs baseline: 1.2186x; 1.0457x over previous
//
#include <hip/hip_runtime.h>
#include <math.h>

// SUFGConv fp32 via split-bf16 MFMA, fully-coalesced operand paths.
// xc rows [0:2048) are dead; both big einsums stream d_list[:,2048:,:] (100.7MB).
//
// R5 lesson: direct per-lane fragment gathers (row-per-lane, 8KB stride) are
// TA-divergence-bound (~60us/pass, same as scalar). R6: A staged via
// global_load_lds (coalesced, XOR-swizzled source -> conflict-free ds_read_b128);
// B pre-packed by k_pre/k_shrink into fragment panels [T][oct][col][8] so a
// B-fragment is ONE coalesced 16B/lane load. MFMA mapping identical to R5
// (hardware-verified): A row = lane&31, k-oct = lane>>5; C col = lane&31,
// row = (reg&3)+8*(reg>>2)+4*oct.

#define DP 2049
#define THRS 0.08628973f   // sqrt(2*ln(2048))/sqrt(2048)

typedef float  f32x4  __attribute__((ext_vector_type(4)));
typedef float  f32x16 __attribute__((ext_vector_type(16)));
typedef short  s16x8  __attribute__((ext_vector_type(8)));
typedef unsigned short u16;

// ws byte offsets
#define XWP_H 0u            // panels: [2][128][2][32][8] u16 = 256KB
#define XWP_L 262144u
#define XSP_H 524288u       // panels: [2][384][2][32][8] u16 = 768KB
#define XSP_L 1310720u
#define P1_B  2097152u      // [32][32][6144] f32 = 25.2MB
#define P2_B  27262976u     // [64][32][2176] f32 = 17.8MB

union U8 { unsigned u[4]; s16x8 v; };

__device__ __forceinline__ unsigned cvtpk(float a, float b) {
  unsigned r;
  asm("v_cvt_pk_bf16_f32 %0, %1, %2" : "=v"(r) : "v"(a), "v"(b));
  return r;
}
__device__ __forceinline__ void split2(float a0, float a1, unsigned& h, unsigned& l) {
  h = cvtpk(a0, a1);
  const float f0 = __uint_as_float(h << 16);
  const float f1 = __uint_as_float(h & 0xFFFF0000u);
  l = cvtpk(a0 - f0, a1 - f1);
}
__device__ __forceinline__ void cp4(const float* g, float* l) {
  __builtin_amdgcn_global_load_lds((const __attribute__((address_space(1))) void*)g,
                                   (__attribute__((address_space(3))) void*)l, 4, 0, 0);
}
__device__ __forceinline__ void cp16(const float* g, float* l) {
  __builtin_amdgcn_global_load_lds((const __attribute__((address_space(1))) void*)g,
                                   (__attribute__((address_space(3))) void*)l, 16, 0, 0);
}

// xw = x@weight -> bf16 hi/lo fragment panels [b][t=n>>4][oct=(n>>3)&1][col][j=n&7]
__global__ __launch_bounds__(256) void k_pre(const float* __restrict__ x,
                                             const float* __restrict__ wgt,
                                             u16* __restrict__ xwp_h,
                                             u16* __restrict__ xwp_l) {
  const int idx = blockIdx.x * 256 + threadIdx.x;   // 16384 threads
  const int n0  = (idx & 255) * 8;
  const int col = (idx >> 8) & 31;
  const int b   = idx >> 13;
  const float* xr = x + ((size_t)b * 2048 + n0) * 32;
  float acc[8];
#pragma unroll
  for (int j = 0; j < 8; ++j) acc[j] = 0.f;
#pragma unroll 8
  for (int f = 0; f < 32; ++f) {
    const float wf = wgt[f * 32 + col];
#pragma unroll
    for (int j = 0; j < 8; ++j) acc[j] = fmaf(xr[j * 32 + f], wf, acc[j]);
  }
  U8 H, L;
#pragma unroll
  for (int p = 0; p < 4; ++p) split2(acc[2 * p], acc[2 * p + 1], H.u[p], L.u[p]);
  const size_t o = (size_t)b * 65536 +
                   ((((size_t)(n0 >> 4) * 2 + ((n0 >> 3) & 1)) * 32 + col) * 8);
  *(s16x8*)(xwp_h + o) = H.v;
  *(s16x8*)(xwp_l + o) = L.v;
}

// p1[(s,b)][o][m] = (d1_seg @ xw) * filt ; blocks (48,2,16), K=128/block
__global__ __launch_bounds__(256, 4) void k_pass1(const float* __restrict__ dlist,
                                                  const u16* __restrict__ xwp_h,
                                                  const u16* __restrict__ xwp_l,
                                                  const float* __restrict__ filt,
                                                  float* __restrict__ p1) {
  __shared__ float dl[2][4][1024];                  // 32KB; wave-private quarters
  const int mt = blockIdx.x, b = blockIdx.y, s = blockIdx.z;
  const int tid = threadIdx.x, wv = tid >> 6, l = tid & 63;
  const int rc = l & 31, oct = l >> 5;
  const int k0 = s * 128;

  // staging (cp4, 16/wave/chunk): LDS row = 2i+(l>>5), slot=(l>>2)&7, word=l&3.
  // source slot pre-XORed so LDS[r][sx] holds global slot sx^(r&7).
  const int cl = ((l >> 2) & 7) ^ (l >> 5);
  const float* dbase = dlist +
      ((size_t)(b * 8192 + 2048 + mt * 128 + wv * 32 + (l >> 5))) * DP + 1 + k0 + (l & 3);

  const u16* Bh = xwp_h + (size_t)b * 65536;
  const u16* Bl = xwp_l + (size_t)b * 65536;

  auto stage = [&](int buf, int kc) {
    float* lb = &dl[buf][wv][0];
#pragma unroll 4
    for (int i = 0; i < 16; ++i)
      cp4(dbase + (size_t)(2 * i) * DP + kc + ((cl ^ ((2 * i) & 7)) << 2), lb + i * 64);
  };

  f32x16 acc = {0.f,0.f,0.f,0.f,0.f,0.f,0.f,0.f,0.f,0.f,0.f,0.f,0.f,0.f,0.f,0.f};

  stage(0, 0);
#pragma unroll 1
  for (int c = 0; c < 4; ++c) {
    __syncthreads();                                // chunk c resident
    if (c < 3) stage((c + 1) & 1, (c + 1) * 32);    // prefetch under compute
    const float* wb = &dl[c & 1][wv][0];
#pragma unroll
    for (int st = 0; st < 2; ++st) {
      const int T = s * 8 + c * 2 + st;
      const int s0 = (4 * st + 2 * oct) ^ (rc & 7);
      const int s1 = (4 * st + 2 * oct + 1) ^ (rc & 7);
      const f32x4 a0 = *(const f32x4*)(wb + rc * 32 + s0 * 4);
      const f32x4 a1 = *(const f32x4*)(wb + rc * 32 + s1 * 4);
      U8 Ah, Al;
      split2(a0.x, a0.y, Ah.u[0], Al.u[0]);
      split2(a0.z, a0.w, Ah.u[1], Al.u[1]);
      split2(a1.x, a1.y, Ah.u[2], Al.u[2]);
      split2(a1.z, a1.w, Ah.u[3], Al.u[3]);
      const size_t bo = ((size_t)(T * 2 + oct) * 32 + rc) * 8;
      const s16x8 bh = *(const s16x8*)(Bh + bo);
      const s16x8 bl = *(const s16x8*)(Bl + bo);
      acc = __builtin_amdgcn_mfma_f32_32x32x16_bf16(Ah.v, bh, acc, 0, 0, 0);
      acc = __builtin_amdgcn_mfma_f32_32x32x16_bf16(Al.v, bh, acc, 0, 0, 0);
      acc = __builtin_amdgcn_mfma_f32_32x32x16_bf16(Ah.v, bl, acc, 0, 0, 0);
    }
  }

  float* pc = p1 + ((size_t)((s * 2 + b) * 32 + rc)) * 6144 + mt * 128 + wv * 32 + 4 * oct;
  const float* fb = filt + 2048 + mt * 128 + wv * 32 + 4 * oct;
#pragma unroll
  for (int g = 0; g < 4; ++g) {
    const f32x4 fv = *(const f32x4*)(fb + 8 * g);
    f32x4 v;
    v.x = acc[4 * g + 0] * fv.x; v.y = acc[4 * g + 1] * fv.y;
    v.z = acc[4 * g + 2] * fv.z; v.w = acc[4 * g + 3] * fv.w;
    *(f32x4*)(pc + 8 * g) = v;
  }
}

// xs = shrink(sum_s p1) -> bf16 hi/lo fragment panels [b][t=m>>4][oct][col][j]
__global__ __launch_bounds__(256) void k_shrink(const float* __restrict__ p1,
                                                u16* __restrict__ xsp_h,
                                                u16* __restrict__ xsp_l) {
  const int idx = blockIdx.x * 256 + threadIdx.x;   // 49152 threads
  const int m0  = (idx % 768) * 8;
  const int col = (idx / 768) % 32;
  const int b   = idx / 24576;
  f32x4 s0 = {0.f,0.f,0.f,0.f}, s1 = {0.f,0.f,0.f,0.f};
#pragma unroll
  for (int s = 0; s < 16; ++s) {
    const float* pr = p1 + ((size_t)((s * 2 + b) * 32 + col)) * 6144 + m0;
    s0 += *(const f32x4*)pr;
    s1 += *(const f32x4*)(pr + 4);
  }
  float a[8] = {s0.x, s0.y, s0.z, s0.w, s1.x, s1.y, s1.z, s1.w};
  if (m0 >= 2048) {
#pragma unroll
    for (int j = 0; j < 8; ++j) {
      const float t = fabsf(a[j]) - THRS;
      a[j] = t > 0.f ? copysignf(t, a[j]) : 0.f;
    }
  }
  U8 H, L;
#pragma unroll
  for (int p = 0; p < 4; ++p) split2(a[2 * p], a[2 * p + 1], H.u[p], L.u[p]);
  const size_t o = (size_t)b * 196608 +
                   ((((size_t)(m0 >> 4) * 2 + ((m0 >> 3) & 1)) * 32 + col) * 8);
  *(s16x8*)(xsp_h + o) = H.v;
  *(s16x8*)(xsp_l + o) = L.v;
}

// p2[(s,b)][o][k] = y2_seg @ xs ; blocks (17,2,32), K=192/block
__global__ __launch_bounds__(256, 4) void k_pass2(const float* __restrict__ dlist,
                                                  const u16* __restrict__ xsp_h,
                                                  const u16* __restrict__ xsp_l,
                                                  float* __restrict__ p2) {
  __shared__ float dl[2][4][1024];
  const int kt = blockIdx.x, b = blockIdx.y, s = blockIdx.z;
  const int tid = threadIdx.x, wv = tid >> 6, l = tid & 63;
  const int rc = l & 31, oct = l >> 5;
  const int m0 = s * 192;

  // staging (cp16, 4/wave/chunk): LDS row = 8i+(l>>3), slot=l&7; source pre-XORed.
  const int row_l = kt * 128 + wv * 32 + (l >> 3);
  const int swz = (l & 7) ^ ((l >> 3) & 7);
  const float* Ab = dlist + (size_t)b * 8192 * DP + (size_t)2048 * DP + m0 + swz * 4;

  const u16* Bh = xsp_h + (size_t)b * 196608;
  const u16* Bl = xsp_l + (size_t)b * 196608;

  auto stage = [&](int buf, int kc) {
    float* lb = &dl[buf][wv][0];
#pragma unroll
    for (int i = 0; i < 4; ++i) {
      int rg = row_l + 8 * i;
      rg = rg > 2048 ? 2048 : rg;                   // tail clamp; rows discarded later
      cp16(Ab + (size_t)rg * 6144 + kc, lb + i * 256);
    }
  };

  f32x16 acc = {0.f,0.f,0.f,0.f,0.f,0.f,0.f,0.f,0.f,0.f,0.f,0.f,0.f,0.f,0.f,0.f};

  stage(0, 0);
#pragma unroll 1
  for (int c = 0; c < 6; ++c) {
    __syncthreads();
    if (c < 5) stage((c + 1) & 1, (c + 1) * 32);
    const float* wb = &dl[c & 1][wv][0];
#pragma unroll
    for (int st = 0; st < 2; ++st) {
      const int T = s * 12 + c * 2 + st;
      const int s0 = (4 * st + 2 * oct) ^ (rc & 7);
      const int s1 = (4 * st + 2 * oct + 1) ^ (rc & 7);
      const f32x4 a0 = *(const f32x4*)(wb + rc * 32 + s0 * 4);
      const f32x4 a1 = *(const f32x4*)(wb + rc * 32 + s1 * 4);
      U8 Ah, Al;
      split2(a0.x, a0.y, Ah.u[0], Al.u[0]);
      split2(a0.z, a0.w, Ah.u[1], Al.u[1]);
      split2(a1.x, a1.y, Ah.u[2], Al.u[2]);
      split2(a1.z, a1.w, Ah.u[3], Al.u[3]);
      const size_t bo = ((size_t)(T * 2 + oct) * 32 + rc) * 8;
      const s16x8 bh = *(const s16x8*)(Bh + bo);
      const s16x8 bl = *(const s16x8*)(Bl + bo);
      acc = __builtin_amdgcn_mfma_f32_32x32x16_bf16(Ah.v, bh, acc, 0, 0, 0);
      acc = __builtin_amdgcn_mfma_f32_32x32x16_bf16(Al.v, bh, acc, 0, 0, 0);
      acc = __builtin_amdgcn_mfma_f32_32x32x16_bf16(Ah.v, bl, acc, 0, 0, 0);
    }
  }

  float* pc = p2 + ((size_t)((s * 2 + b) * 32 + rc)) * 2176 + kt * 128 + wv * 32 + 4 * oct;
#pragma unroll
  for (int g = 0; g < 4; ++g) {
    f32x4 v;
    v.x = acc[4 * g + 0]; v.y = acc[4 * g + 1];
    v.z = acc[4 * g + 2]; v.w = acc[4 * g + 3];
    *(f32x4*)(pc + 8 * g) = v;
  }
}

// out[b][k][col] = bias[col] + sum_s p2[(s,b)][col][k]
__global__ __launch_bounds__(256) void k_reduce(const float* __restrict__ p2,
                                                const float* __restrict__ bias,
                                                float* __restrict__ out) {
  const int idx = blockIdx.x * 256 + threadIdx.x;   // 34816 threads
  if (idx >= 34816) return;
  const int k4  = idx % 544;
  const int col = (idx / 544) % 32;
  const int b   = idx / 17408;
  const int k0r = k4 * 4;
  f32x4 sum = {0.f,0.f,0.f,0.f};
#pragma unroll 8
  for (int s = 0; s < 32; ++s)
    sum += *(const f32x4*)(p2 + ((size_t)((s * 2 + b) * 32 + col)) * 2176 + k0r);
  const float bv = bias[col];
#pragma unroll
  for (int j = 0; j < 4; ++j) {
    const int k = k0r + j;
    if (k <= 2048) out[((size_t)b * 2049 + k) * 32 + col] = sum[j] + bv;
  }
}

extern "C" void kernel_launch(void* const* d_in, const int* in_sizes, int n_in,
                              void* d_out, int out_size, void* d_ws, size_t ws_size,
                              hipStream_t stream) {
  const float* x     = (const float*)d_in[0];
  const float* dlist = (const float*)d_in[1];
  const float* wgt   = (const float*)d_in[2];
  const float* filt  = (const float*)d_in[3];
  const float* bias  = (const float*)d_in[4];
  float* out = (float*)d_out;
  char*  ws  = (char*)d_ws;
  u16*   xwp_h = (u16*)(ws + XWP_H);
  u16*   xwp_l = (u16*)(ws + XWP_L);
  u16*   xsp_h = (u16*)(ws + XSP_H);
  u16*   xsp_l = (u16*)(ws + XSP_L);
  float* p1    = (float*)(ws + P1_B);
  float* p2    = (float*)(ws + P2_B);

  k_pre   <<<dim3(64),         dim3(256), 0, stream>>>(x, wgt, xwp_h, xwp_l);
  k_pass1 <<<dim3(48, 2, 16),  dim3(256), 0, stream>>>(dlist, xwp_h, xwp_l, filt, p1);
  k_shrink<<<dim3(192),        dim3(256), 0, stream>>>(p1, xsp_h, xsp_l);
  k_pass2 <<<dim3(17, 2, 32),  dim3(256), 0, stream>>>(dlist, xsp_h, xsp_l, p2);
  k_reduce<<<dim3(136),        dim3(256), 0, stream>>>(p2, bias, out);
}